// Round 1
// baseline (2129.111 us; speedup 1.0000x reference)
//
#include <hip/hip_runtime.h>
#include <hip/hip_bf16.h>

// MHA: B=4, S=2048, H=1024, NH=16, HD=64. fp32 in/out.
constexpr int kB = 4;
constexpr int kS = 2048;
constexpr int kH = 1024;
constexpr int kNH = 16;
constexpr int kHD = 64;
constexpr int kM = kB * kS;  // 8192 rows in the projection GEMMs

// ---------------------------------------------------------------------------
// Tiled SGEMM: C[m,n] = sum_k A[m,k] * W[n,k] + bias[n]
// A: (8192 x 1024) row-major, W: (1024 x 1024) row-major (so this is x @ W^T).
// 128x128 block tile, BK=16, 256 threads, 8x8 micro-tile per thread.
// LDS rows padded to 20 floats (80 B, 16B-aligned; bank stride 20 => <=2-way).
// SCATTER=true writes C into (B,NH,S,HD) head-major layout for attention.
// ---------------------------------------------------------------------------
template <bool SCATTER>
__device__ __forceinline__ void gemm_body(const float* __restrict__ A,
                                          const float* __restrict__ W,
                                          const float* __restrict__ bias,
                                          float* __restrict__ C) {
  constexpr int Kdim = kH;  // 1024
  __shared__ float As[128][20];
  __shared__ float Bs[128][20];
  const int tid = threadIdx.x;
  const int tx = tid & 15;
  const int ty = tid >> 4;
  const int bm = blockIdx.x * 128;  // 64 blocks over M
  const int bn = blockIdx.y * 128;  // 8 blocks over N
  const float* Ab = A + (size_t)bm * Kdim;
  const float* Wb = W + (size_t)bn * Kdim;
  const int r0 = tid >> 2;         // 0..63
  const int ks = (tid & 3) << 2;   // 0,4,8,12

  float acc[8][8];
#pragma unroll
  for (int i = 0; i < 8; ++i)
#pragma unroll
    for (int j = 0; j < 8; ++j) acc[i][j] = 0.f;

  for (int k0 = 0; k0 < Kdim; k0 += 16) {
    // Issue global loads before the barrier so VMEM latency overlaps it.
    float4 a0 = *(const float4*)(Ab + (size_t)r0 * Kdim + k0 + ks);
    float4 a1 = *(const float4*)(Ab + (size_t)(r0 + 64) * Kdim + k0 + ks);
    float4 w0 = *(const float4*)(Wb + (size_t)r0 * Kdim + k0 + ks);
    float4 w1 = *(const float4*)(Wb + (size_t)(r0 + 64) * Kdim + k0 + ks);
    __syncthreads();  // previous iteration's LDS reads complete
    *(float4*)&As[r0][ks] = a0;
    *(float4*)&As[r0 + 64][ks] = a1;
    *(float4*)&Bs[r0][ks] = w0;
    *(float4*)&Bs[r0 + 64][ks] = w1;
    __syncthreads();
#pragma unroll
    for (int kk = 0; kk < 16; kk += 4) {
      float4 af[8], bf[8];
#pragma unroll
      for (int i = 0; i < 8; ++i) af[i] = *(const float4*)&As[ty + 16 * i][kk];
#pragma unroll
      for (int j = 0; j < 8; ++j) bf[j] = *(const float4*)&Bs[tx + 16 * j][kk];
#pragma unroll
      for (int i = 0; i < 8; ++i)
#pragma unroll
        for (int j = 0; j < 8; ++j) {
          acc[i][j] += af[i].x * bf[j].x;
          acc[i][j] += af[i].y * bf[j].y;
          acc[i][j] += af[i].z * bf[j].z;
          acc[i][j] += af[i].w * bf[j].w;
        }
    }
  }

#pragma unroll
  for (int j = 0; j < 8; ++j) {
    const int n = bn + tx + 16 * j;
    const float bv = bias[n];
#pragma unroll
    for (int i = 0; i < 8; ++i) {
      const int m = bm + ty + 16 * i;
      const float val = acc[i][j] + bv;
      if (SCATTER) {
        const int b = m >> 11;           // /kS
        const int s = m & (kS - 1);
        const int h = n >> 6;            // /kHD
        const int d = n & (kHD - 1);
        C[(((size_t)b * kNH + h) * kS + s) * kHD + d] = val;
      } else {
        C[(size_t)m * kH + n] = val;
      }
    }
  }
}

__global__ __launch_bounds__(256) void qkv_kernel(
    const float* __restrict__ x, const float* __restrict__ wq,
    const float* __restrict__ bq, const float* __restrict__ wk,
    const float* __restrict__ bk, const float* __restrict__ wv,
    const float* __restrict__ bv, float* __restrict__ qo,
    float* __restrict__ ko, float* __restrict__ vo) {
  const float* W;
  const float* bias;
  float* out;
  if (blockIdx.z == 0) { W = wq; bias = bq; out = qo; }
  else if (blockIdx.z == 1) { W = wk; bias = bk; out = ko; }
  else { W = wv; bias = bv; out = vo; }
  gemm_body<true>(x, W, bias, out);
}

__global__ __launch_bounds__(256) void oproj_kernel(
    const float* __restrict__ a, const float* __restrict__ wo,
    const float* __restrict__ bo, float* __restrict__ out) {
  gemm_body<false>(a, wo, bo, out);
}

// ---------------------------------------------------------------------------
// fp32 flash attention, causal. One block = one (b,h, 64-row Q tile).
// 256 threads as 16x16 (tx=col group, ty=row group); each thread owns a
// 4x4 score / 4x4 output micro-tile (rows ty+16i, cols tx+16j).
// K-tile and P-tile share one LDS buffer (extra barrier) to stay <= 64 KB.
// Row-wise softmax reductions via __shfl_xor over the 16 tx lanes.
// ---------------------------------------------------------------------------
__global__ __launch_bounds__(256) void attn_kernel(
    const float* __restrict__ Q, const float* __restrict__ K,
    const float* __restrict__ V, float* __restrict__ Aout) {
  __shared__ float Qs[64][68];
  __shared__ float KPs[64][68];  // holds K-tile, then reused for P-tile
  __shared__ float Vs[64][68];
  const int tid = threadIdx.x;
  const int tx = tid & 15;
  const int ty = tid >> 4;
  const int qt = blockIdx.x & 31;   // S/64 = 32 q-tiles
  const int bh = blockIdx.x >> 5;   // b*NH + h
  const int b = bh >> 4;            // /kNH
  const int h = bh & (kNH - 1);
  const float* Qp = Q + ((size_t)bh * kS + (size_t)qt * 64) * kHD;
  const float* Kp = K + (size_t)bh * kS * kHD;
  const float* Vp = V + (size_t)bh * kS * kHD;

  // Load Q tile (64x64 floats, coalesced float4)
#pragma unroll
  for (int l = 0; l < 4; ++l) {
    const int idx = tid + 256 * l;
    const int r = idx >> 4;
    const int c = (idx & 15) << 2;
    *(float4*)&Qs[r][c] = *(const float4*)(Qp + (size_t)r * kHD + c);
  }

  float mrow[4], lrow[4], O[4][4];
#pragma unroll
  for (int i = 0; i < 4; ++i) {
    mrow[i] = -1e38f;
    lrow[i] = 0.f;
#pragma unroll
    for (int j = 0; j < 4; ++j) O[i][j] = 0.f;
  }

  for (int kt = 0; kt <= qt; ++kt) {
    const float* Kt = Kp + (size_t)kt * 64 * kHD;
    const float* Vt = Vp + (size_t)kt * 64 * kHD;
    __syncthreads();  // previous PV reads of KPs/Vs complete
#pragma unroll
    for (int l = 0; l < 4; ++l) {
      const int idx = tid + 256 * l;
      const int r = idx >> 4;
      const int c = (idx & 15) << 2;
      *(float4*)&KPs[r][c] = *(const float4*)(Kt + (size_t)r * kHD + c);
      *(float4*)&Vs[r][c] = *(const float4*)(Vt + (size_t)r * kHD + c);
    }
    __syncthreads();

    // scores[r][c] = sum_d Qs[r][d] * K[c][d]
    float sc[4][4];
#pragma unroll
    for (int i = 0; i < 4; ++i)
#pragma unroll
      for (int j = 0; j < 4; ++j) sc[i][j] = 0.f;
#pragma unroll
    for (int d0 = 0; d0 < kHD; d0 += 4) {
      float4 qf[4], kf[4];
#pragma unroll
      for (int i = 0; i < 4; ++i) qf[i] = *(const float4*)&Qs[ty + 16 * i][d0];
#pragma unroll
      for (int j = 0; j < 4; ++j) kf[j] = *(const float4*)&KPs[tx + 16 * j][d0];
#pragma unroll
      for (int i = 0; i < 4; ++i)
#pragma unroll
        for (int j = 0; j < 4; ++j) {
          sc[i][j] += qf[i].x * kf[j].x;
          sc[i][j] += qf[i].y * kf[j].y;
          sc[i][j] += qf[i].z * kf[j].z;
          sc[i][j] += qf[i].w * kf[j].w;
        }
    }
    __syncthreads();  // all K reads done; KPs can become P

    const bool diag = (kt == qt);
#pragma unroll
    for (int i = 0; i < 4; ++i) {
      const int r = ty + 16 * i;
#pragma unroll
      for (int j = 0; j < 4; ++j) {
        const int c = tx + 16 * j;
        float s = sc[i][j] * 0.125f;  // 1/sqrt(64)
        if (diag && c > r) s = -1e38f;
        sc[i][j] = s;
      }
    }
    // online softmax update (row reduce over 16 tx lanes)
#pragma unroll
    for (int i = 0; i < 4; ++i) {
      float tm = fmaxf(fmaxf(sc[i][0], sc[i][1]), fmaxf(sc[i][2], sc[i][3]));
#pragma unroll
      for (int msk = 1; msk <= 8; msk <<= 1)
        tm = fmaxf(tm, __shfl_xor(tm, msk, 64));
      const float mnew = fmaxf(mrow[i], tm);
      const float esc = __expf(mrow[i] - mnew);
      mrow[i] = mnew;
      float ps = 0.f;
#pragma unroll
      for (int j = 0; j < 4; ++j) {
        const float p = __expf(sc[i][j] - mnew);
        KPs[ty + 16 * i][tx + 16 * j] = p;
        ps += p;
      }
#pragma unroll
      for (int msk = 1; msk <= 8; msk <<= 1) ps += __shfl_xor(ps, msk, 64);
      lrow[i] = lrow[i] * esc + ps;
#pragma unroll
      for (int j = 0; j < 4; ++j) O[i][j] *= esc;
    }
    __syncthreads();  // P visible to all

    // O[r][d] += sum_k P[r][k] * V[k][d]
#pragma unroll
    for (int k0 = 0; k0 < 64; k0 += 4) {
      float4 pf[4];
#pragma unroll
      for (int i = 0; i < 4; ++i) pf[i] = *(const float4*)&KPs[ty + 16 * i][k0];
#pragma unroll
      for (int u = 0; u < 4; ++u) {
        float vv[4];
#pragma unroll
        for (int j = 0; j < 4; ++j) vv[j] = Vs[k0 + u][tx + 16 * j];
#pragma unroll
        for (int i = 0; i < 4; ++i) {
          const float p = (u == 0) ? pf[i].x
                        : (u == 1) ? pf[i].y
                        : (u == 2) ? pf[i].z
                                   : pf[i].w;
#pragma unroll
          for (int j = 0; j < 4; ++j) O[i][j] += p * vv[j];
        }
      }
    }
  }

  // normalize and store into (B,S,H) layout for the output projection
#pragma unroll
  for (int i = 0; i < 4; ++i) {
    const float rl = 1.f / lrow[i];
    const int r = qt * 64 + ty + 16 * i;
#pragma unroll
    for (int j = 0; j < 4; ++j) {
      const int d = tx + 16 * j;
      Aout[((size_t)b * kS + r) * kH + h * kHD + d] = O[i][j] * rl;
    }
  }
}

extern "C" void kernel_launch(void* const* d_in, const int* in_sizes, int n_in,
                              void* d_out, int out_size, void* d_ws,
                              size_t ws_size, hipStream_t stream) {
  const float* x = (const float*)d_in[0];
  const float* wq = (const float*)d_in[1];
  const float* bq = (const float*)d_in[2];
  const float* wk = (const float*)d_in[3];
  const float* bk = (const float*)d_in[4];
  const float* wv = (const float*)d_in[5];
  const float* bv = (const float*)d_in[6];
  const float* wo = (const float*)d_in[7];
  const float* bo = (const float*)d_in[8];
  float* out = (float*)d_out;

  float* ws = (float*)d_ws;
  const size_t per = (size_t)kB * kNH * kS * kHD;  // 8,388,608 floats
  float* qb = ws;
  float* kb = ws + per;
  float* vb = ws + 2 * per;
  float* ab = ws + 3 * per;  // attention output, (B,S,H) layout

  dim3 blk(256);
  // QKV projections: z selects q/k/v
  qkv_kernel<<<dim3(kM / 128, kH / 128, 3), blk, 0, stream>>>(
      x, wq, bq, wk, bk, wv, bv, qb, kb, vb);
  // causal flash attention
  attn_kernel<<<dim3(kB * kNH * (kS / 64)), blk, 0, stream>>>(qb, kb, vb, ab);
  // output projection
  oproj_kernel<<<dim3(kM / 128, kH / 128), blk, 0, stream>>>(ab, wo, bo, out);
}

// Round 2
// 374.627 us; speedup vs baseline: 5.6833x; 5.6833x over previous
//
#include <hip/hip_runtime.h>
#include <hip/hip_bf16.h>

using bf16 = __bf16;
typedef __attribute__((ext_vector_type(4))) bf16 bf16x4;
typedef __attribute__((ext_vector_type(8))) bf16 bf16x8;
typedef __attribute__((ext_vector_type(4))) float f32x4;

constexpr int kB = 4, kS = 2048, kH = 1024, kNH = 16, kHD = 64;
constexpr int kM = kB * kS;  // 8192

// ---------------------------------------------------------------------------
// fp32 -> bf16 conversion passes
// ---------------------------------------------------------------------------
__global__ __launch_bounds__(256) void cvt_kernel(const float* __restrict__ src,
                                                  bf16* __restrict__ dst) {
  const size_t i = (size_t)blockIdx.x * 256 + threadIdx.x;
  const float4 f = ((const float4*)src)[i];
  bf16x4 o;
  o[0] = (bf16)f.x; o[1] = (bf16)f.y; o[2] = (bf16)f.z; o[3] = (bf16)f.w;
  ((bf16x4*)dst)[i] = o;
}

__global__ __launch_bounds__(256) void cvt_w_kernel(
    const float* __restrict__ w0, const float* __restrict__ w1,
    const float* __restrict__ w2, const float* __restrict__ w3,
    bf16* __restrict__ dst) {
  const float* s = blockIdx.y == 0 ? w0 : blockIdx.y == 1 ? w1
                 : blockIdx.y == 2 ? w2 : w3;
  const size_t i = (size_t)blockIdx.x * 256 + threadIdx.x;
  const float4 f = ((const float4*)s)[i];
  bf16x4 o;
  o[0] = (bf16)f.x; o[1] = (bf16)f.y; o[2] = (bf16)f.z; o[3] = (bf16)f.w;
  ((bf16x4*)(dst + (size_t)blockIdx.y * kH * kH))[i] = o;
}

// ---------------------------------------------------------------------------
// bf16 MFMA GEMM: C = A @ W^T + bias.  A:[M][1024] bf16, W:[N][1024] bf16.
// 128x128 tile, BK=32, 256 threads = 4 waves (2x2), 4x4 16x16 frags/wave.
// LDS rows padded to 40 bf16 (80 B) -> frag ds_read_b128 ~2-way conflicts.
// MODE 0: fp32 [M][kH] + bias.  MODE 1: bf16 scatter to (b,h,s,d) head-major.
// ---------------------------------------------------------------------------
template <int MODE>
__device__ __forceinline__ void mm_body(const bf16* __restrict__ A,
                                        const bf16* __restrict__ W,
                                        const float* __restrict__ bias,
                                        void* __restrict__ Cp) {
  __shared__ __align__(16) bf16 As[128 * 40];
  __shared__ __align__(16) bf16 Bs[128 * 40];
  const int tid = threadIdx.x;
  const int lane = tid & 63;
  const int wid = tid >> 6;
  const int wr = wid >> 1, wc = wid & 1;
  const int fr = lane & 15, fg = lane >> 4;
  const int bm = blockIdx.x * 128, bn = blockIdx.y * 128;
  const bf16* Ab = A + (size_t)bm * kH;
  const bf16* Wb = W + (size_t)bn * kH;
  const int sr = tid >> 2;         // staging row 0..63
  const int sc = (tid & 3) * 8;    // staging col element

  f32x4 acc[4][4] = {};

  for (int k0 = 0; k0 < kH; k0 += 32) {
    const bf16x8 a0 = *(const bf16x8*)(Ab + (size_t)sr * kH + k0 + sc);
    const bf16x8 a1 = *(const bf16x8*)(Ab + (size_t)(sr + 64) * kH + k0 + sc);
    const bf16x8 b0 = *(const bf16x8*)(Wb + (size_t)sr * kH + k0 + sc);
    const bf16x8 b1 = *(const bf16x8*)(Wb + (size_t)(sr + 64) * kH + k0 + sc);
    __syncthreads();  // previous iteration's frag reads done
    *(bf16x8*)(As + sr * 40 + sc) = a0;
    *(bf16x8*)(As + (sr + 64) * 40 + sc) = a1;
    *(bf16x8*)(Bs + sr * 40 + sc) = b0;
    *(bf16x8*)(Bs + (sr + 64) * 40 + sc) = b1;
    __syncthreads();

    bf16x8 af[4], bfv[4];
#pragma unroll
    for (int m = 0; m < 4; ++m)
      af[m] = *(const bf16x8*)(As + (wr * 64 + m * 16 + fr) * 40 + fg * 8);
#pragma unroll
    for (int n = 0; n < 4; ++n)
      bfv[n] = *(const bf16x8*)(Bs + (wc * 64 + n * 16 + fr) * 40 + fg * 8);
#pragma unroll
    for (int m = 0; m < 4; ++m)
#pragma unroll
      for (int n = 0; n < 4; ++n)
        acc[m][n] = __builtin_amdgcn_mfma_f32_16x16x32_bf16(af[m], bfv[n],
                                                            acc[m][n], 0, 0, 0);
  }

#pragma unroll
  for (int n = 0; n < 4; ++n) {
    const int nabs = bn + wc * 64 + n * 16 + fr;
    const float bv = bias[nabs];
#pragma unroll
    for (int m = 0; m < 4; ++m)
#pragma unroll
      for (int reg = 0; reg < 4; ++reg) {
        const int tok = bm + wr * 64 + m * 16 + fg * 4 + reg;
        const float v = acc[m][n][reg] + bv;
        if (MODE == 0) {
          ((float*)Cp)[(size_t)tok * kH + nabs] = v;
        } else {
          const int b = tok >> 11, s = tok & (kS - 1);
          const int h = nabs >> 6, d = nabs & 63;
          ((bf16*)Cp)[(((size_t)(b * kNH + h)) * kS + s) * kHD + d] = (bf16)v;
        }
      }
  }
}

__global__ __launch_bounds__(256) void qkv_kernel(
    const bf16* __restrict__ xb, const bf16* __restrict__ wb,
    const float* __restrict__ bq, const float* __restrict__ bk,
    const float* __restrict__ bv, bf16* __restrict__ qh,
    bf16* __restrict__ kh, bf16* __restrict__ vh) {
  const int z = blockIdx.z;
  const bf16* W = wb + (size_t)z * kH * kH;
  const float* bias = z == 0 ? bq : z == 1 ? bk : bv;
  bf16* out = z == 0 ? qh : z == 1 ? kh : vh;
  mm_body<1>(xb, W, bias, out);
}

__global__ __launch_bounds__(256) void oproj_kernel(
    const bf16* __restrict__ ab, const bf16* __restrict__ wob,
    const float* __restrict__ bo, float* __restrict__ out) {
  mm_body<0>(ab, wob, bo, out);
}

// ---------------------------------------------------------------------------
// bf16 MFMA causal flash attention.
// Block = (qt, bh): 256 threads = 4 waves; wave w owns Q rows qt*64+w*16..+15.
// K tile [64 keys][64 d] and V^T tile [64 d][64 keys] in XOR-swizzled LDS
// (16B slot ^= row&7).  Q held in frags.  Softmax in D-layout registers,
// 16-lane shfl_xor row reduce; P staged per-wave in LDS -> A-frags for PV.
// ---------------------------------------------------------------------------
__global__ __launch_bounds__(256) void attn_kernel(
    const bf16* __restrict__ Qh, const bf16* __restrict__ Kh,
    const bf16* __restrict__ Vh, bf16* __restrict__ Ab) {
  __shared__ __align__(16) bf16 Ks[64 * 64];
  __shared__ __align__(16) bf16 Vt[64 * 64];
  __shared__ __align__(16) bf16 Ps[4 * 16 * 64];
  const int tid = threadIdx.x;
  const int lane = tid & 63;
  const int wid = tid >> 6;
  const int qt = gridDim.x - 1 - blockIdx.x;  // longest blocks first
  const int bh = blockIdx.y;
  const int b = bh >> 4, h = bh & (kNH - 1);
  const int fr = lane & 15, fg = lane >> 4;

  const bf16* Qb = Qh + ((size_t)bh * kS + qt * 64 + wid * 16) * kHD;
  const bf16* Kb = Kh + (size_t)bh * kS * kHD;
  const bf16* Vb = Vh + (size_t)bh * kS * kHD;
  char* const Pw = (char*)Ps + wid * 2048;  // per-wave P region (16 rows)

  // Q fragments, resident whole kernel
  bf16x8 qf[2];
#pragma unroll
  for (int kc = 0; kc < 2; ++kc)
    qf[kc] = *(const bf16x8*)(Qb + (size_t)fr * kHD + kc * 32 + fg * 8);

  float mrow[4], lrow[4];
  f32x4 Oa[4] = {};
#pragma unroll
  for (int r = 0; r < 4; ++r) { mrow[r] = -3e38f; lrow[r] = 0.f; }

  const int strow = tid & 63;   // staging row (key index)
  const int stc = tid >> 6;     // staging 16B-chunk 0..3 (then +4)

  for (int kt = 0; kt <= qt; ++kt) {
    __syncthreads();  // all waves done reading previous K/V tiles
    const bf16* Kt = Kb + (size_t)kt * 64 * kHD;
    const bf16* Vg = Vb + (size_t)kt * 64 * kHD;
#pragma unroll
    for (int p = 0; p < 2; ++p) {
      const int c16 = stc + p * 4;
      const bf16x8 kv = *(const bf16x8*)(Kt + (size_t)strow * kHD + c16 * 8);
      *(bf16x8*)((char*)Ks + strow * 128 + ((c16 ^ (strow & 7)) << 4)) = kv;
      const bf16x8 vv = *(const bf16x8*)(Vg + (size_t)strow * kHD + c16 * 8);
#pragma unroll
      for (int i = 0; i < 8; ++i) {
        const int d = c16 * 8 + i;  // Vt row = d, col = key strow
        ((bf16*)((char*)Vt + d * 128 + ((((strow >> 3) ^ (d & 7))) << 4)))
            [strow & 7] = vv[i];
      }
    }
    __syncthreads();

    // ---- S = Q K^T (per wave: 16 rows x 64 cols) ----
    f32x4 S[4] = {};
#pragma unroll
    for (int kc = 0; kc < 2; ++kc)
#pragma unroll
      for (int nb = 0; nb < 4; ++nb) {
        const int row = nb * 16 + fr;           // key index
        const int slot = kc * 4 + fg;
        const bf16x8 kf = *(const bf16x8*)((char*)Ks + row * 128 +
                                           ((slot ^ (row & 7)) << 4));
        S[nb] = __builtin_amdgcn_mfma_f32_16x16x32_bf16(qf[kc], kf, S[nb], 0, 0, 0);
      }

    // ---- online softmax, P -> LDS (bf16) ----
    const bool diag = (kt == qt);
    float esc[4];
#pragma unroll
    for (int reg = 0; reg < 4; ++reg) {
      const int row_abs = qt * 64 + wid * 16 + fg * 4 + reg;
      float sv[4];
      float tm = -3e38f;
#pragma unroll
      for (int nb = 0; nb < 4; ++nb) {
        float s = S[nb][reg] * 0.125f;
        if (diag) {
          const int col_abs = kt * 64 + nb * 16 + fr;
          if (col_abs > row_abs) s = -3e38f;
        }
        sv[nb] = s;
        tm = fmaxf(tm, s);
      }
#pragma unroll
      for (int msk = 1; msk <= 8; msk <<= 1)
        tm = fmaxf(tm, __shfl_xor(tm, msk, 64));
      const float mn = fmaxf(mrow[reg], tm);
      const float e = __expf(mrow[reg] - mn);
      mrow[reg] = mn;
      esc[reg] = e;
      float ps = 0.f;
      const int prow = fg * 4 + reg;
#pragma unroll
      for (int nb = 0; nb < 4; ++nb) {
        const float p = __expf(sv[nb] - mn);
        ps += p;
        const int col = nb * 16 + fr;
        const int slot = col >> 3;
        ((bf16*)(Pw + prow * 128 + ((slot ^ (prow & 7)) << 4)))[col & 7] =
            (bf16)p;
      }
#pragma unroll
      for (int msk = 1; msk <= 8; msk <<= 1) ps += __shfl_xor(ps, msk, 64);
      lrow[reg] = lrow[reg] * e + ps;
    }
#pragma unroll
    for (int nbv = 0; nbv < 4; ++nbv)
#pragma unroll
      for (int reg = 0; reg < 4; ++reg) Oa[nbv][reg] *= esc[reg];

    // wave-internal: make this wave's P writes visible to all its lanes
    asm volatile("s_waitcnt lgkmcnt(0)" ::: "memory");

    // ---- O += P V ----
    bf16x8 pa[2];
#pragma unroll
    for (int kc = 0; kc < 2; ++kc) {
      const int slot = kc * 4 + fg;
      pa[kc] = *(const bf16x8*)(Pw + fr * 128 + ((slot ^ (fr & 7)) << 4));
    }
#pragma unroll
    for (int nbv = 0; nbv < 4; ++nbv) {
      const int row = nbv * 16 + fr;  // d index
#pragma unroll
      for (int kc = 0; kc < 2; ++kc) {
        const int slot = kc * 4 + fg;
        const bf16x8 vf = *(const bf16x8*)((char*)Vt + row * 128 +
                                           ((slot ^ (row & 7)) << 4));
        Oa[nbv] = __builtin_amdgcn_mfma_f32_16x16x32_bf16(pa[kc], vf, Oa[nbv], 0, 0, 0);
      }
    }
  }

  // ---- normalize + store bf16 (B,S,H) ----
#pragma unroll
  for (int reg = 0; reg < 4; ++reg) {
    const float rl = 1.f / lrow[reg];
    const int row_abs = qt * 64 + wid * 16 + fg * 4 + reg;
#pragma unroll
    for (int nbv = 0; nbv < 4; ++nbv) {
      const int d = nbv * 16 + fr;
      Ab[((size_t)b * kS + row_abs) * kH + h * 64 + d] =
          (bf16)(Oa[nbv][reg] * rl);
    }
  }
}

extern "C" void kernel_launch(void* const* d_in, const int* in_sizes, int n_in,
                              void* d_out, int out_size, void* d_ws,
                              size_t ws_size, hipStream_t stream) {
  const float* x = (const float*)d_in[0];
  const float* wq = (const float*)d_in[1];
  const float* bq = (const float*)d_in[2];
  const float* wk = (const float*)d_in[3];
  const float* bk = (const float*)d_in[4];
  const float* wv = (const float*)d_in[5];
  const float* bv = (const float*)d_in[6];
  const float* wo = (const float*)d_in[7];
  const float* bo = (const float*)d_in[8];
  float* out = (float*)d_out;

  const size_t perHead = (size_t)kB * kNH * kS * kHD;  // 8,388,608
  bf16* xb = (bf16*)d_ws;
  bf16* wb = xb + (size_t)kM * kH;          // 4 weight matrices, contiguous
  bf16* qh = wb + (size_t)4 * kH * kH;
  bf16* kh = qh + perHead;
  bf16* vh = kh + perHead;
  bf16* ab = vh + perHead;                  // attn out, (B,S,H) bf16

  dim3 blk(256);
  cvt_kernel<<<dim3(kM * kH / 1024), blk, 0, stream>>>(x, xb);
  cvt_w_kernel<<<dim3(kH * kH / 1024, 4), blk, 0, stream>>>(wq, wk, wv, wo, wb);
  qkv_kernel<<<dim3(kM / 128, kH / 128, 3), blk, 0, stream>>>(
      xb, wb, bq, bk, bv, qh, kh, vh);
  attn_kernel<<<dim3(kS / 64, kB * kNH), blk, 0, stream>>>(qh, kh, vh, ab);
  oproj_kernel<<<dim3(kM / 128, kH / 128), blk, 0, stream>>>(
      ab, wb + (size_t)3 * kH * kH, bo, out);
}

// Round 3
// 201.497 us; speedup vs baseline: 10.5665x; 1.8592x over previous
//
#include <hip/hip_runtime.h>
#include <hip/hip_bf16.h>

using bf16 = __bf16;
typedef __attribute__((ext_vector_type(4))) bf16 bf16x4;
typedef __attribute__((ext_vector_type(8))) bf16 bf16x8;
typedef __attribute__((ext_vector_type(4))) float f32x4;
typedef __attribute__((ext_vector_type(16))) float f32x16;

constexpr int kB = 4, kS = 2048, kH = 1024, kNH = 16, kHD = 64;
constexpr int kM = kB * kS;  // 8192

__device__ __forceinline__ float exp2a(float x) {
  float r;
  asm("v_exp_f32 %0, %1" : "=v"(r) : "v"(x));
  return r;
}
__device__ __forceinline__ unsigned pk2(float a, float b) {
  unsigned short ua = __builtin_bit_cast(unsigned short, (bf16)a);
  unsigned short ub = __builtin_bit_cast(unsigned short, (bf16)b);
  return (unsigned)ua | ((unsigned)ub << 16);
}

// ---------------------------------------------------------------------------
// fp32 -> bf16 conversion passes
// ---------------------------------------------------------------------------
__global__ __launch_bounds__(256) void cvt_kernel(const float* __restrict__ src,
                                                  bf16* __restrict__ dst) {
  const size_t i = (size_t)blockIdx.x * 256 + threadIdx.x;
  const float4 f = ((const float4*)src)[i];
  bf16x4 o;
  o[0] = (bf16)f.x; o[1] = (bf16)f.y; o[2] = (bf16)f.z; o[3] = (bf16)f.w;
  ((bf16x4*)dst)[i] = o;
}

__global__ __launch_bounds__(256) void cvt_w_kernel(
    const float* __restrict__ w0, const float* __restrict__ w1,
    const float* __restrict__ w2, const float* __restrict__ w3,
    bf16* __restrict__ dst) {
  const float* s = blockIdx.y == 0 ? w0 : blockIdx.y == 1 ? w1
                 : blockIdx.y == 2 ? w2 : w3;
  const size_t i = (size_t)blockIdx.x * 256 + threadIdx.x;
  const float4 f = ((const float4*)s)[i];
  bf16x4 o;
  o[0] = (bf16)f.x; o[1] = (bf16)f.y; o[2] = (bf16)f.z; o[3] = (bf16)f.w;
  ((bf16x4*)(dst + (size_t)blockIdx.y * kH * kH))[i] = o;
}

// ---------------------------------------------------------------------------
// bf16 MFMA GEMM: C = A @ W^T + bias.  128x128 tile, BK=32, 4 waves.
// MODE 0: fp32 [M][kH].  MODE 1: bf16 (b,h,s,d).  MODE 2: bf16 V^T (b,h,d,s).
// ---------------------------------------------------------------------------
template <int MODE>
__device__ __forceinline__ void mm_body(const bf16* __restrict__ A,
                                        const bf16* __restrict__ W,
                                        const float* __restrict__ bias,
                                        void* __restrict__ Cp) {
  __shared__ __align__(16) bf16 As[128 * 40];
  __shared__ __align__(16) bf16 Bs[128 * 40];
  const int tid = threadIdx.x;
  const int lane = tid & 63;
  const int wid = tid >> 6;
  const int wr = wid >> 1, wc = wid & 1;
  const int fr = lane & 15, fg = lane >> 4;
  const int bm = blockIdx.x * 128, bn = blockIdx.y * 128;
  const bf16* Ab = A + (size_t)bm * kH;
  const bf16* Wb = W + (size_t)bn * kH;
  const int sr = tid >> 2;
  const int sc = (tid & 3) * 8;

  f32x4 acc[4][4] = {};

  for (int k0 = 0; k0 < kH; k0 += 32) {
    const bf16x8 a0 = *(const bf16x8*)(Ab + (size_t)sr * kH + k0 + sc);
    const bf16x8 a1 = *(const bf16x8*)(Ab + (size_t)(sr + 64) * kH + k0 + sc);
    const bf16x8 b0 = *(const bf16x8*)(Wb + (size_t)sr * kH + k0 + sc);
    const bf16x8 b1 = *(const bf16x8*)(Wb + (size_t)(sr + 64) * kH + k0 + sc);
    __syncthreads();
    *(bf16x8*)(As + sr * 40 + sc) = a0;
    *(bf16x8*)(As + (sr + 64) * 40 + sc) = a1;
    *(bf16x8*)(Bs + sr * 40 + sc) = b0;
    *(bf16x8*)(Bs + (sr + 64) * 40 + sc) = b1;
    __syncthreads();

    bf16x8 af[4], bfv[4];
#pragma unroll
    for (int m = 0; m < 4; ++m)
      af[m] = *(const bf16x8*)(As + (wr * 64 + m * 16 + fr) * 40 + fg * 8);
#pragma unroll
    for (int n = 0; n < 4; ++n)
      bfv[n] = *(const bf16x8*)(Bs + (wc * 64 + n * 16 + fr) * 40 + fg * 8);
#pragma unroll
    for (int m = 0; m < 4; ++m)
#pragma unroll
      for (int n = 0; n < 4; ++n)
        acc[m][n] = __builtin_amdgcn_mfma_f32_16x16x32_bf16(af[m], bfv[n],
                                                            acc[m][n], 0, 0, 0);
  }

#pragma unroll
  for (int n = 0; n < 4; ++n) {
    const int nabs = bn + wc * 64 + n * 16 + fr;
    const float bv = bias[nabs];
#pragma unroll
    for (int m = 0; m < 4; ++m) {
      if (MODE == 2) {
        // V^T: out[((b*NH+h)*HD + d)*S + s], 4 consecutive s per store
        const int tok0 = bm + wr * 64 + m * 16 + fg * 4;
        const int b = tok0 >> 11, s0 = tok0 & (kS - 1);
        const int h = nabs >> 6, d = nabs & 63;
        bf16x4 pv;
#pragma unroll
        for (int reg = 0; reg < 4; ++reg) pv[reg] = (bf16)(acc[m][n][reg] + bv);
        *(bf16x4*)((bf16*)Cp + (((size_t)(b * kNH + h) * kHD + d) * kS + s0)) = pv;
      } else {
#pragma unroll
        for (int reg = 0; reg < 4; ++reg) {
          const int tok = bm + wr * 64 + m * 16 + fg * 4 + reg;
          const float v = acc[m][n][reg] + bv;
          if (MODE == 0) {
            ((float*)Cp)[(size_t)tok * kH + nabs] = v;
          } else {
            const int b = tok >> 11, s = tok & (kS - 1);
            const int h = nabs >> 6, d = nabs & 63;
            ((bf16*)Cp)[(((size_t)(b * kNH + h)) * kS + s) * kHD + d] = (bf16)v;
          }
        }
      }
    }
  }
}

__global__ __launch_bounds__(256) void qkv_kernel(
    const bf16* __restrict__ xb, const bf16* __restrict__ wb,
    const float* __restrict__ bq, const float* __restrict__ bk,
    const float* __restrict__ bv, bf16* __restrict__ qh,
    bf16* __restrict__ kh, bf16* __restrict__ vh) {
  const int z = blockIdx.z;
  const bf16* W = wb + (size_t)z * kH * kH;
  if (z == 0) mm_body<1>(xb, W, bq, qh);
  else if (z == 1) mm_body<1>(xb, W, bk, kh);
  else mm_body<2>(xb, W, bv, vh);
}

__global__ __launch_bounds__(256) void oproj_kernel(
    const bf16* __restrict__ ab, const bf16* __restrict__ wob,
    const float* __restrict__ bo, float* __restrict__ out) {
  mm_body<0>(ab, wob, bo, out);
}

// ---------------------------------------------------------------------------
// Swapped-QK^T MFMA flash attention (m214-style), 32x32x16 bf16.
// Block: 4 waves x 32 q-rows = 128 rows.  KV staged 64/tile (K row-major,
// V^T row-major, both XOR-swizzled).  S^T = mfma(K, Q): lane owns q=l&31,
// 16 keys/reg-file; softmax lane-local + one lane^32 exchange (exp2 domain).
// P packed to bf16 in-register via pk2 + v_permlane32_swap_b32 -> PV B-frags.
// O^T = mfma(V^T, P^T): accumulator q-index lane-local -> direct rescale.
// ---------------------------------------------------------------------------
__global__ __launch_bounds__(256) void attn_kernel(
    const bf16* __restrict__ Qh, const bf16* __restrict__ Kh,
    const bf16* __restrict__ Vt, bf16* __restrict__ Ab) {
  __shared__ __align__(16) bf16 Ks[64 * 64];
  __shared__ __align__(16) bf16 Vs[64 * 64];
  const int tid = threadIdx.x;
  const int lane = tid & 63;
  const int wid = tid >> 6;
  const int l31 = lane & 31;
  const int hi = lane >> 5;
  const int bh = blockIdx.x;            // bh fixes the XCD (x % 8 pattern)
  const int qt = gridDim.y - 1 - blockIdx.y;  // biggest q-tiles dispatch first
  const int b = bh >> 4, h = bh & (kNH - 1);

  const int qfirst = qt * 128 + wid * 32;
  const int qrow = qfirst + l31;

  const bf16* Qg = Qh + (size_t)bh * kS * kHD;
  const bf16* Kg = Kh + (size_t)bh * kS * kHD;
  const bf16* Vg = Vt + (size_t)bh * kHD * kS;  // [64][2048]

  // Q fragments: B-operand layout B[k=d][col=q]
  bf16x8 qf[4];
#pragma unroll
  for (int kb = 0; kb < 4; ++kb)
    qf[kb] = *(const bf16x8*)(Qg + (size_t)qrow * kHD + kb * 16 + hi * 8);

  f32x16 Oa0 = {}, Oa1 = {};
  float mreg = -3.0e38f, lreg = 0.f;
  constexpr float kScale = 0.125f * 1.44269504f;  // 1/sqrt(64) * log2(e)

  const int sr = tid >> 2;      // staging row 0..63
  const int sc = tid & 3;       // staging slot (and +4)
  const int nt64 = qt * 2 + 2;

  for (int kt = 0; kt < nt64; ++kt) {
    const int kt0 = kt * 64;
    const bf16x8 kr0 = *(const bf16x8*)(Kg + (size_t)(kt0 + sr) * kHD + sc * 8);
    const bf16x8 kr1 = *(const bf16x8*)(Kg + (size_t)(kt0 + sr) * kHD + (sc + 4) * 8);
    const bf16x8 vr0 = *(const bf16x8*)(Vg + (size_t)sr * kS + kt0 + sc * 8);
    const bf16x8 vr1 = *(const bf16x8*)(Vg + (size_t)sr * kS + kt0 + (sc + 4) * 8);
    __syncthreads();  // previous tile reads done
    *(bf16x8*)((char*)Ks + sr * 128 + ((sc ^ (sr & 7)) << 4)) = kr0;
    *(bf16x8*)((char*)Ks + sr * 128 + (((sc + 4) ^ (sr & 7)) << 4)) = kr1;
    *(bf16x8*)((char*)Vs + sr * 128 + ((sc ^ (sr & 7)) << 4)) = vr0;
    *(bf16x8*)((char*)Vs + sr * 128 + (((sc + 4) ^ (sr & 7)) << 4)) = vr1;
    __syncthreads();

#pragma unroll
    for (int st = 0; st < 2; ++st) {
      const int kabs = kt0 + st * 32;
      if (kabs > qfirst) continue;     // wave-uniform causal skip
      const bool diag = (kabs == qfirst);

      // ---- S^T = K . Q^T over 4 d-chunks ----
      f32x16 S = {};
#pragma unroll
      for (int kb = 0; kb < 4; ++kb) {
        const int row = st * 32 + l31;
        const int slot = ((kb * 2 + hi) ^ (row & 7));
        const bf16x8 kf = *(const bf16x8*)((char*)Ks + row * 128 + (slot << 4));
        S = __builtin_amdgcn_mfma_f32_32x32x16_bf16(kf, qf[kb], S, 0, 0, 0);
      }

      // ---- lane-local softmax (exp2 domain) ----
      float p[16];
      float tm = -3.0e38f;
#pragma unroll
      for (int r = 0; r < 16; ++r) {
        float s2 = S[r] * kScale;
        if (diag) {
          const int key = kabs + (r & 3) + 8 * (r >> 2) + 4 * hi;
          if (key > qrow) s2 = -3.0e38f;
        }
        p[r] = s2;
        tm = fmaxf(tm, s2);
      }
      tm = fmaxf(tm, __shfl_xor(tm, 32, 64));
      const float mnew = fmaxf(mreg, tm);
      const float e = exp2a(mreg - mnew);
      mreg = mnew;
      float ps = 0.f;
#pragma unroll
      for (int r = 0; r < 16; ++r) {
        p[r] = exp2a(p[r] - mnew);
        ps += p[r];
      }
      ps += __shfl_xor(ps, 32, 64);
      lreg = lreg * e + ps;
#pragma unroll
      for (int r = 0; r < 16; ++r) { Oa0[r] *= e; Oa1[r] *= e; }

      // ---- pack P -> bf16 B-frags via permlane32_swap ----
      bf16x8 pf[2];
#pragma unroll
      for (int kb2 = 0; kb2 < 2; ++kb2) {
        const int o = kb2 * 8;
        unsigned a01 = pk2(p[o + 0], p[o + 1]);
        unsigned a45 = pk2(p[o + 4], p[o + 5]);
        asm("v_permlane32_swap_b32 %0, %1" : "+v"(a01), "+v"(a45));
        unsigned a23 = pk2(p[o + 2], p[o + 3]);
        unsigned a67 = pk2(p[o + 6], p[o + 7]);
        asm("v_permlane32_swap_b32 %0, %1" : "+v"(a23), "+v"(a67));
        union { unsigned u[4]; bf16x8 v; } t;
        t.u[0] = a01; t.u[1] = a23; t.u[2] = a45; t.u[3] = a67;
        pf[kb2] = t.v;
      }

      // ---- O^T += V^T . P^T ----
#pragma unroll
      for (int kb2 = 0; kb2 < 2; ++kb2) {
        {
          const int row = l31;
          const int slot = ((st * 4 + kb2 * 2 + hi) ^ (row & 7));
          const bf16x8 vf = *(const bf16x8*)((char*)Vs + row * 128 + (slot << 4));
          Oa0 = __builtin_amdgcn_mfma_f32_32x32x16_bf16(vf, pf[kb2], Oa0, 0, 0, 0);
        }
        {
          const int row = 32 + l31;
          const int slot = ((st * 4 + kb2 * 2 + hi) ^ (row & 7));
          const bf16x8 vf = *(const bf16x8*)((char*)Vs + row * 128 + (slot << 4));
          Oa1 = __builtin_amdgcn_mfma_f32_32x32x16_bf16(vf, pf[kb2], Oa1, 0, 0, 0);
        }
      }
    }
  }

  // ---- normalize + store bf16 (B,S,H) ----
  const float rl = 1.f / lreg;
  bf16* const orow = Ab + ((size_t)b * kS + qrow) * kH + h * 64;
#pragma unroll
  for (int rq = 0; rq < 4; ++rq) {
    bf16x4 o0, o1;
#pragma unroll
    for (int j = 0; j < 4; ++j) {
      o0[j] = (bf16)(Oa0[rq * 4 + j] * rl);
      o1[j] = (bf16)(Oa1[rq * 4 + j] * rl);
    }
    *(bf16x4*)(orow + rq * 8 + hi * 4) = o0;
    *(bf16x4*)(orow + 32 + rq * 8 + hi * 4) = o1;
  }
}

extern "C" void kernel_launch(void* const* d_in, const int* in_sizes, int n_in,
                              void* d_out, int out_size, void* d_ws,
                              size_t ws_size, hipStream_t stream) {
  const float* x = (const float*)d_in[0];
  const float* wq = (const float*)d_in[1];
  const float* bq = (const float*)d_in[2];
  const float* wk = (const float*)d_in[3];
  const float* bk = (const float*)d_in[4];
  const float* wv = (const float*)d_in[5];
  const float* bv = (const float*)d_in[6];
  const float* wo = (const float*)d_in[7];
  const float* bo = (const float*)d_in[8];
  float* out = (float*)d_out;

  const size_t perHead = (size_t)kB * kNH * kS * kHD;
  bf16* xb = (bf16*)d_ws;
  bf16* wb = xb + (size_t)kM * kH;
  bf16* qh = wb + (size_t)4 * kH * kH;
  bf16* kh = qh + perHead;
  bf16* vh = kh + perHead;   // V^T: [bh][64][2048]
  bf16* ab = vh + perHead;   // attn out, (B,S,H) bf16

  dim3 blk(256);
  cvt_kernel<<<dim3(kM * kH / 1024), blk, 0, stream>>>(x, xb);
  cvt_w_kernel<<<dim3(kH * kH / 1024, 4), blk, 0, stream>>>(wq, wk, wv, wo, wb);
  qkv_kernel<<<dim3(kM / 128, kH / 128, 3), blk, 0, stream>>>(
      xb, wb, bq, bk, bv, qh, kh, vh);
  attn_kernel<<<dim3(kB * kNH, kS / 128), blk, 0, stream>>>(qh, kh, vh, ab);
  oproj_kernel<<<dim3(kM / 128, kH / 128), blk, 0, stream>>>(
      ab, wb + (size_t)3 * kH * kH, bo, out);
}

// Round 4
// 191.192 us; speedup vs baseline: 11.1360x; 1.0539x over previous
//
#include <hip/hip_runtime.h>
#include <hip/hip_bf16.h>

using bf16 = __bf16;
typedef __attribute__((ext_vector_type(4))) bf16 bf16x4;
typedef __attribute__((ext_vector_type(8))) bf16 bf16x8;
typedef __attribute__((ext_vector_type(4))) float f32x4;
typedef __attribute__((ext_vector_type(16))) float f32x16;

constexpr int kB = 4, kS = 2048, kH = 1024, kNH = 16, kHD = 64;
constexpr int kM = kB * kS;  // 8192

__device__ __forceinline__ float exp2a(float x) {
  float r;
  asm("v_exp_f32 %0, %1" : "=v"(r) : "v"(x));
  return r;
}
__device__ __forceinline__ unsigned pk2(float a, float b) {
  unsigned short ua = __builtin_bit_cast(unsigned short, (bf16)a);
  unsigned short ub = __builtin_bit_cast(unsigned short, (bf16)b);
  return (unsigned)ua | ((unsigned)ub << 16);
}
// async global->LDS, 16B per lane; LDS dest = wave-uniform base + lane*16
__device__ __forceinline__ void glds16(const bf16* g, bf16* l) {
  __builtin_amdgcn_global_load_lds(
      (const __attribute__((address_space(1))) unsigned*)g,
      (__attribute__((address_space(3))) unsigned*)l, 16, 0, 0);
}

// ---------------------------------------------------------------------------
// fused fp32 -> bf16 conversion (x + 4 weight matrices) in one launch
// ---------------------------------------------------------------------------
__global__ __launch_bounds__(256) void cvt_all_kernel(
    const float* __restrict__ x, const float* __restrict__ w0,
    const float* __restrict__ w1, const float* __restrict__ w2,
    const float* __restrict__ w3, bf16* __restrict__ xb,
    bf16* __restrict__ wb) {
  const int blk = blockIdx.x;
  const float* src;
  bf16* dst;
  int rel;
  if (blk < kM) {  // 8192 blocks cover x (8.4M floats)
    src = x; dst = xb; rel = blk;
  } else {
    const int wi = (blk - kM) >> 10;
    rel = (blk - kM) & 1023;
    src = wi == 0 ? w0 : wi == 1 ? w1 : wi == 2 ? w2 : w3;
    dst = wb + (size_t)wi * kH * kH;
  }
  const size_t i = (size_t)rel * 256 + threadIdx.x;
  const float4 f = ((const float4*)src)[i];
  bf16x4 o;
  o[0] = (bf16)f.x; o[1] = (bf16)f.y; o[2] = (bf16)f.z; o[3] = (bf16)f.w;
  ((bf16x4*)dst)[i] = o;
}

// ---------------------------------------------------------------------------
// bf16 MFMA GEMM (m97 structure): C = A @ W^T + bias.  128x128 tile, BK=32,
// 4 waves, async global_load_lds dwordx4 staging into LINEAR LDS [128][32].
// MODE 0: fp32 [M][kH].  MODE 1: bf16 (b,h,s,d).  MODE 2: bf16 V^T (b,h,d,s).
// ---------------------------------------------------------------------------
template <int MODE>
__device__ __forceinline__ void mm_body(const bf16* __restrict__ A,
                                        const bf16* __restrict__ W,
                                        const float* __restrict__ bias,
                                        void* __restrict__ Cp) {
  __shared__ __align__(16) bf16 As[128 * 32];
  __shared__ __align__(16) bf16 Bs[128 * 32];
  const int tid = threadIdx.x;
  const int lane = tid & 63;
  const int wid = tid >> 6;
  const int wr = wid >> 1, wc = wid & 1;
  const int fr = lane & 15, fg = lane >> 4;
  const int bm = blockIdx.x * 128, bn = blockIdx.y * 128;
  const bf16* Ab = A + (size_t)bm * kH;
  const bf16* Wb = W + (size_t)bn * kH;
  // staging: wave w covers rows w*32..w*32+31 (2 instrs of 16 rows each);
  // lane l covers row rbase+(l>>2), 16B chunk (l&3) within the 64B row.
  const int srow = lane >> 2;
  const int scol = (lane & 3) * 8;
  const int rb0 = wid * 32, rb1 = wid * 32 + 16;

  f32x4 acc[4][4] = {};

  for (int k0 = 0; k0 < kH; k0 += 32) {
    __syncthreads();  // all waves done reading previous tile
    glds16(Ab + (size_t)(rb0 + srow) * kH + k0 + scol, As + rb0 * 32);
    glds16(Ab + (size_t)(rb1 + srow) * kH + k0 + scol, As + rb1 * 32);
    glds16(Wb + (size_t)(rb0 + srow) * kH + k0 + scol, Bs + rb0 * 32);
    glds16(Wb + (size_t)(rb1 + srow) * kH + k0 + scol, Bs + rb1 * 32);
    __syncthreads();  // vmcnt drain before barrier -> tile visible

    bf16x8 af[4], bfv[4];
#pragma unroll
    for (int m = 0; m < 4; ++m)
      af[m] = *(const bf16x8*)(As + (wr * 64 + m * 16 + fr) * 32 + fg * 8);
#pragma unroll
    for (int n = 0; n < 4; ++n)
      bfv[n] = *(const bf16x8*)(Bs + (wc * 64 + n * 16 + fr) * 32 + fg * 8);
#pragma unroll
    for (int m = 0; m < 4; ++m)
#pragma unroll
      for (int n = 0; n < 4; ++n)
        acc[m][n] = __builtin_amdgcn_mfma_f32_16x16x32_bf16(af[m], bfv[n],
                                                            acc[m][n], 0, 0, 0);
  }

#pragma unroll
  for (int n = 0; n < 4; ++n) {
    const int nabs = bn + wc * 64 + n * 16 + fr;
    const float bv = bias[nabs];
#pragma unroll
    for (int m = 0; m < 4; ++m) {
      if (MODE == 2) {
        // V^T: out[((b*NH+h)*HD + d)*S + s], 4 consecutive s per store
        const int tok0 = bm + wr * 64 + m * 16 + fg * 4;
        const int b = tok0 >> 11, s0 = tok0 & (kS - 1);
        const int h = nabs >> 6, d = nabs & 63;
        bf16x4 pv;
#pragma unroll
        for (int reg = 0; reg < 4; ++reg) pv[reg] = (bf16)(acc[m][n][reg] + bv);
        *(bf16x4*)((bf16*)Cp + (((size_t)(b * kNH + h) * kHD + d) * kS + s0)) = pv;
      } else {
#pragma unroll
        for (int reg = 0; reg < 4; ++reg) {
          const int tok = bm + wr * 64 + m * 16 + fg * 4 + reg;
          const float v = acc[m][n][reg] + bv;
          if (MODE == 0) {
            ((float*)Cp)[(size_t)tok * kH + nabs] = v;
          } else {
            const int b = tok >> 11, s = tok & (kS - 1);
            const int h = nabs >> 6, d = nabs & 63;
            ((bf16*)Cp)[(((size_t)(b * kNH + h)) * kS + s) * kHD + d] = (bf16)v;
          }
        }
      }
    }
  }
}

__global__ __launch_bounds__(256) void qkv_kernel(
    const bf16* __restrict__ xb, const bf16* __restrict__ wb,
    const float* __restrict__ bq, const float* __restrict__ bk,
    const float* __restrict__ bv, bf16* __restrict__ qh,
    bf16* __restrict__ kh, bf16* __restrict__ vh) {
  const int z = blockIdx.z;
  const bf16* W = wb + (size_t)z * kH * kH;
  if (z == 0) mm_body<1>(xb, W, bq, qh);
  else if (z == 1) mm_body<1>(xb, W, bk, kh);
  else mm_body<2>(xb, W, bv, vh);
}

__global__ __launch_bounds__(256) void oproj_kernel(
    const bf16* __restrict__ ab, const bf16* __restrict__ wob,
    const float* __restrict__ bo, float* __restrict__ out) {
  mm_body<0>(ab, wob, bo, out);
}

// ---------------------------------------------------------------------------
// Swapped-QK^T MFMA flash attention (m214-style), 32x32x16 bf16. (unchanged)
// ---------------------------------------------------------------------------
__global__ __launch_bounds__(256) void attn_kernel(
    const bf16* __restrict__ Qh, const bf16* __restrict__ Kh,
    const bf16* __restrict__ Vt, bf16* __restrict__ Ab) {
  __shared__ __align__(16) bf16 Ks[64 * 64];
  __shared__ __align__(16) bf16 Vs[64 * 64];
  const int tid = threadIdx.x;
  const int lane = tid & 63;
  const int wid = tid >> 6;
  const int l31 = lane & 31;
  const int hi = lane >> 5;
  const int bh = blockIdx.x;
  const int qt = gridDim.y - 1 - blockIdx.y;  // biggest q-tiles dispatch first
  const int b = bh >> 4, h = bh & (kNH - 1);

  const int qfirst = qt * 128 + wid * 32;
  const int qrow = qfirst + l31;

  const bf16* Qg = Qh + (size_t)bh * kS * kHD;
  const bf16* Kg = Kh + (size_t)bh * kS * kHD;
  const bf16* Vg = Vt + (size_t)bh * kHD * kS;  // [64][2048]

  bf16x8 qf[4];
#pragma unroll
  for (int kb = 0; kb < 4; ++kb)
    qf[kb] = *(const bf16x8*)(Qg + (size_t)qrow * kHD + kb * 16 + hi * 8);

  f32x16 Oa0 = {}, Oa1 = {};
  float mreg = -3.0e38f, lreg = 0.f;
  constexpr float kScale = 0.125f * 1.44269504f;  // 1/sqrt(64) * log2(e)

  const int sr = tid >> 2;
  const int sc = tid & 3;
  const int nt64 = qt * 2 + 2;

  for (int kt = 0; kt < nt64; ++kt) {
    const int kt0 = kt * 64;
    const bf16x8 kr0 = *(const bf16x8*)(Kg + (size_t)(kt0 + sr) * kHD + sc * 8);
    const bf16x8 kr1 = *(const bf16x8*)(Kg + (size_t)(kt0 + sr) * kHD + (sc + 4) * 8);
    const bf16x8 vr0 = *(const bf16x8*)(Vg + (size_t)sr * kS + kt0 + sc * 8);
    const bf16x8 vr1 = *(const bf16x8*)(Vg + (size_t)sr * kS + kt0 + (sc + 4) * 8);
    __syncthreads();
    *(bf16x8*)((char*)Ks + sr * 128 + ((sc ^ (sr & 7)) << 4)) = kr0;
    *(bf16x8*)((char*)Ks + sr * 128 + (((sc + 4) ^ (sr & 7)) << 4)) = kr1;
    *(bf16x8*)((char*)Vs + sr * 128 + ((sc ^ (sr & 7)) << 4)) = vr0;
    *(bf16x8*)((char*)Vs + sr * 128 + (((sc + 4) ^ (sr & 7)) << 4)) = vr1;
    __syncthreads();

#pragma unroll
    for (int st = 0; st < 2; ++st) {
      const int kabs = kt0 + st * 32;
      if (kabs > qfirst) continue;
      const bool diag = (kabs == qfirst);

      f32x16 S = {};
#pragma unroll
      for (int kb = 0; kb < 4; ++kb) {
        const int row = st * 32 + l31;
        const int slot = ((kb * 2 + hi) ^ (row & 7));
        const bf16x8 kf = *(const bf16x8*)((char*)Ks + row * 128 + (slot << 4));
        S = __builtin_amdgcn_mfma_f32_32x32x16_bf16(kf, qf[kb], S, 0, 0, 0);
      }

      float p[16];
      float tm = -3.0e38f;
#pragma unroll
      for (int r = 0; r < 16; ++r) {
        float s2 = S[r] * kScale;
        if (diag) {
          const int key = kabs + (r & 3) + 8 * (r >> 2) + 4 * hi;
          if (key > qrow) s2 = -3.0e38f;
        }
        p[r] = s2;
        tm = fmaxf(tm, s2);
      }
      tm = fmaxf(tm, __shfl_xor(tm, 32, 64));
      const float mnew = fmaxf(mreg, tm);
      const float e = exp2a(mreg - mnew);
      mreg = mnew;
      float ps = 0.f;
#pragma unroll
      for (int r = 0; r < 16; ++r) {
        p[r] = exp2a(p[r] - mnew);
        ps += p[r];
      }
      ps += __shfl_xor(ps, 32, 64);
      lreg = lreg * e + ps;
#pragma unroll
      for (int r = 0; r < 16; ++r) { Oa0[r] *= e; Oa1[r] *= e; }

      bf16x8 pf[2];
#pragma unroll
      for (int kb2 = 0; kb2 < 2; ++kb2) {
        const int o = kb2 * 8;
        unsigned a01 = pk2(p[o + 0], p[o + 1]);
        unsigned a45 = pk2(p[o + 4], p[o + 5]);
        asm("v_permlane32_swap_b32 %0, %1" : "+v"(a01), "+v"(a45));
        unsigned a23 = pk2(p[o + 2], p[o + 3]);
        unsigned a67 = pk2(p[o + 6], p[o + 7]);
        asm("v_permlane32_swap_b32 %0, %1" : "+v"(a23), "+v"(a67));
        union { unsigned u[4]; bf16x8 v; } t;
        t.u[0] = a01; t.u[1] = a23; t.u[2] = a45; t.u[3] = a67;
        pf[kb2] = t.v;
      }

#pragma unroll
      for (int kb2 = 0; kb2 < 2; ++kb2) {
        {
          const int row = l31;
          const int slot = ((st * 4 + kb2 * 2 + hi) ^ (row & 7));
          const bf16x8 vf = *(const bf16x8*)((char*)Vs + row * 128 + (slot << 4));
          Oa0 = __builtin_amdgcn_mfma_f32_32x32x16_bf16(vf, pf[kb2], Oa0, 0, 0, 0);
        }
        {
          const int row = 32 + l31;
          const int slot = ((st * 4 + kb2 * 2 + hi) ^ (row & 7));
          const bf16x8 vf = *(const bf16x8*)((char*)Vs + row * 128 + (slot << 4));
          Oa1 = __builtin_amdgcn_mfma_f32_32x32x16_bf16(vf, pf[kb2], Oa1, 0, 0, 0);
        }
      }
    }
  }

  const float rl = 1.f / lreg;
  bf16* const orow = Ab + ((size_t)b * kS + qrow) * kH + h * 64;
#pragma unroll
  for (int rq = 0; rq < 4; ++rq) {
    bf16x4 o0, o1;
#pragma unroll
    for (int j = 0; j < 4; ++j) {
      o0[j] = (bf16)(Oa0[rq * 4 + j] * rl);
      o1[j] = (bf16)(Oa1[rq * 4 + j] * rl);
    }
    *(bf16x4*)(orow + rq * 8 + hi * 4) = o0;
    *(bf16x4*)(orow + 32 + rq * 8 + hi * 4) = o1;
  }
}

extern "C" void kernel_launch(void* const* d_in, const int* in_sizes, int n_in,
                              void* d_out, int out_size, void* d_ws,
                              size_t ws_size, hipStream_t stream) {
  const float* x = (const float*)d_in[0];
  const float* wq = (const float*)d_in[1];
  const float* bq = (const float*)d_in[2];
  const float* wk = (const float*)d_in[3];
  const float* bk = (const float*)d_in[4];
  const float* wv = (const float*)d_in[5];
  const float* bv = (const float*)d_in[6];
  const float* wo = (const float*)d_in[7];
  const float* bo = (const float*)d_in[8];
  float* out = (float*)d_out;

  const size_t perHead = (size_t)kB * kNH * kS * kHD;
  bf16* xb = (bf16*)d_ws;
  bf16* wb = xb + (size_t)kM * kH;
  bf16* qh = wb + (size_t)4 * kH * kH;
  bf16* kh = qh + perHead;
  bf16* vh = kh + perHead;   // V^T: [bh][64][2048]
  bf16* ab = vh + perHead;   // attn out, (B,S,H) bf16

  dim3 blk(256);
  cvt_all_kernel<<<dim3(kM + 4 * 1024), blk, 0, stream>>>(x, wq, wk, wv, wo,
                                                          xb, wb);
  qkv_kernel<<<dim3(kM / 128, kH / 128, 3), blk, 0, stream>>>(
      xb, wb, bq, bk, bv, qh, kh, vh);
  attn_kernel<<<dim3(kB * kNH, kS / 128), blk, 0, stream>>>(qh, kh, vh, ab);
  oproj_kernel<<<dim3(kM / 128, kH / 128), blk, 0, stream>>>(
      ab, wb + (size_t)3 * kH * kH, bo, out);
}